// Round 1
// baseline (214.691 us; speedup 1.0000x reference)
//
#include <hip/hip_runtime.h>
#include <hip/hip_bf16.h>

// Problem: exact Euclidean distance transform of a binary mask.
// B=4, C=1, H=W=384. Output = sqrt(exact squared EDT), float32.
//
// Reference math:
//   f0 = mask>0 ? LARGE : 0, LARGE = 2*(H*H+W*W) = 589824
//   pass1 along W: g[x] = min_j f0[j] + (x-j)^2
//   pass2 along H: d2[y] = min_j g[j] + (y-j)^2
//   out = sqrt(d2)
// All values are integers < 2^24 -> float32 brute force is EXACT.

#define HH 384
#define WW 384
#define NB 4
#define LARGE_F 589824.0f

__global__ __launch_bounds__(WW) void edt_pass1(const float* __restrict__ mask,
                                                float* __restrict__ g) {
    const int row = blockIdx.x;        // b*H + y
    const int x = threadIdx.x;         // 0..383
    __shared__ float f[WW];

    const float* m = mask + (size_t)row * WW;
    f[x] = (m[x] > 0.5f) ? LARGE_F : 0.0f;
    __syncthreads();

    float best = 1.0e30f;
    #pragma unroll 8
    for (int j = 0; j < WW; ++j) {
        float d = (float)(x - j);
        best = fminf(best, fmaf(d, d, f[j]));
    }
    g[(size_t)row * WW + x] = best;
}

__global__ __launch_bounds__(HH) void edt_pass2(float* __restrict__ g) {
    const int b = blockIdx.x / WW;
    const int x = blockIdx.x % WW;
    const int y = threadIdx.x;         // 0..383
    __shared__ float f[HH];

    // Stage this (b, x) column into LDS (uncoalesced read, L2-resident).
    f[y] = g[((size_t)b * HH + y) * WW + x];
    __syncthreads();

    float best = 1.0e30f;
    #pragma unroll 8
    for (int j = 0; j < HH; ++j) {
        float d = (float)(y - j);
        best = fminf(best, fmaf(d, d, f[j]));
    }
    // In-place: all reads of this column happened before the barrier.
    g[((size_t)b * HH + y) * WW + x] = sqrtf(best);
}

extern "C" void kernel_launch(void* const* d_in, const int* in_sizes, int n_in,
                              void* d_out, int out_size, void* d_ws, size_t ws_size,
                              hipStream_t stream) {
    const float* mask = (const float*)d_in[0];
    float* out = (float*)d_out;

    // Pass 1: one block per row (B*H rows), intermediate written into d_out.
    edt_pass1<<<NB * HH, WW, 0, stream>>>(mask, out);
    // Pass 2: one block per column (B*W columns), in-place on d_out.
    edt_pass2<<<NB * WW, HH, 0, stream>>>(out);
}

// Round 2
// 63.795 us; speedup vs baseline: 3.3653x; 3.3653x over previous
//
#include <hip/hip_runtime.h>
#include <hip/hip_bf16.h>

// Exact Euclidean distance transform of a binary mask.
// B=4, C=1, H=W=384. Output = sqrt(exact squared EDT), float32.
//
// Windowed-exact algorithm: for the min-plus transform
//   best[i] = min_j f[j] + (i-j)^2  with f >= 0,
// scanning d = 0,1,2,... outward and stopping when d^2 >= best is EXACT,
// because any unscanned j at |i-j| = d contributes >= d^2 >= best.
// With a random 50%-density mask, expected scan length is ~2-3 steps
// instead of 384 -> ~100x less work than brute force.
// All values are integers < 2^24 -> fp32 math is exact.

#define HH 384
#define WW 384
#define NB 4
#define NPIX (NB * HH * WW)
#define LARGE_F 589824.0f

// ---------- fast path: windowed outward search ----------

__global__ __launch_bounds__(256) void edt1_win(const float* __restrict__ mask,
                                                float* __restrict__ g) {
    int idx = blockIdx.x * 256 + threadIdx.x;
    if (idx >= NPIX) return;
    int x = idx % WW;
    const float* m = mask + (idx - x);   // row base

    float best;
    if (m[x] < 0.5f) {
        best = 0.0f;
    } else {
        best = LARGE_F;
        for (int d = 1; d < WW; ++d) {
            float dd = (float)(d * d);
            if (dd >= best) break;       // only triggers for zero-free rows
            bool hit = false;
            if (x - d >= 0 && m[x - d] < 0.5f) hit = true;
            if (x + d < WW && m[x + d] < 0.5f) hit = true;
            if (hit) { best = dd; break; }   // first hit is the nearest
        }
    }
    g[idx] = best;
}

__global__ __launch_bounds__(256) void edt2_win(const float* __restrict__ g,
                                                float* __restrict__ out) {
    int idx = blockIdx.x * 256 + threadIdx.x;
    if (idx >= NPIX) return;
    int x = idx % WW;
    int y = (idx / WW) % HH;
    const float* gb = g + (idx - y * WW - x);  // image base for this b

    float best = gb[y * WW + x];
    for (int d = 1; d < HH; ++d) {
        float dd = (float)(d * d);
        if (dd >= best) break;
        if (y - d >= 0) best = fminf(best, gb[(y - d) * WW + x] + dd);
        if (y + d < HH) best = fminf(best, gb[(y + d) * WW + x] + dd);
    }
    out[idx] = sqrtf(best);
}

// ---------- fallback (ws too small): brute-force LDS version ----------

__global__ __launch_bounds__(WW) void edt_pass1(const float* __restrict__ mask,
                                                float* __restrict__ g) {
    const int row = blockIdx.x;
    const int x = threadIdx.x;
    __shared__ float f[WW];
    const float* m = mask + (size_t)row * WW;
    f[x] = (m[x] > 0.5f) ? LARGE_F : 0.0f;
    __syncthreads();
    float best = 1.0e30f;
    #pragma unroll 8
    for (int j = 0; j < WW; ++j) {
        float d = (float)(x - j);
        best = fminf(best, fmaf(d, d, f[j]));
    }
    g[(size_t)row * WW + x] = best;
}

__global__ __launch_bounds__(HH) void edt_pass2(float* __restrict__ g) {
    const int b = blockIdx.x / WW;
    const int x = blockIdx.x % WW;
    const int y = threadIdx.x;
    __shared__ float f[HH];
    f[y] = g[((size_t)b * HH + y) * WW + x];
    __syncthreads();
    float best = 1.0e30f;
    #pragma unroll 8
    for (int j = 0; j < HH; ++j) {
        float d = (float)(y - j);
        best = fminf(best, fmaf(d, d, f[j]));
    }
    g[((size_t)b * HH + y) * WW + x] = sqrtf(best);
}

extern "C" void kernel_launch(void* const* d_in, const int* in_sizes, int n_in,
                              void* d_out, int out_size, void* d_ws, size_t ws_size,
                              hipStream_t stream) {
    const float* mask = (const float*)d_in[0];
    float* out = (float*)d_out;

    if (ws_size >= (size_t)NPIX * sizeof(float)) {
        float* g = (float*)d_ws;
        const int nb = (NPIX + 255) / 256;
        edt1_win<<<nb, 256, 0, stream>>>(mask, g);
        edt2_win<<<nb, 256, 0, stream>>>(g, out);
    } else {
        // Deterministic fallback: brute force, intermediate in d_out (in-place).
        edt_pass1<<<NB * HH, WW, 0, stream>>>(mask, out);
        edt_pass2<<<NB * WW, HH, 0, stream>>>(out);
    }
}

// Round 3
// 60.133 us; speedup vs baseline: 3.5702x; 1.0609x over previous
//
#include <hip/hip_runtime.h>
#include <hip/hip_bf16.h>

// Exact Euclidean distance transform of a binary mask.
// B=4, C=1, H=W=384. Output = sqrt(exact squared EDT), float32.
//
// Bitboard algorithm: pack "is-zero" pixels into u64 bitmasks
// (384 bits = exactly 6 words per row; 73728 B total, L2-resident).
// For pixel (y,x):  best = min_dy dy^2 + rowdist(y+dy, x)^2,
// scanning dy outward and stopping when dy^2 >= best (exact, since any
// farther row contributes >= dy^2). rowdist() is the distance from
// column x to the nearest set bit in that row, computed with
// ffsll/clzll on at most a couple of u64 words.
// Zero-free rows return rowdist = 768; 768^2 = 589824 = LARGE, so their
// contribution dy^2 + LARGE matches the reference term g=LARGE exactly.
// All values are integers <= 736513 < 2^24 -> fp32 sqrt input is exact.

#define HH 384
#define WW 384
#define NB 4
#define WPR 6                      // u64 words per row (384/64)
#define NPIX (NB * HH * WW)
#define NWORDS (NB * HH * WPR)     // 9216
#define LARGE_F 589824.0f
#define NOZERO_DIST 768            // 768*768 == 589824 == LARGE

typedef unsigned long long u64;

// ---------- fast path: bitboard ----------

__global__ __launch_bounds__(256) void pack_zbits(const float* __restrict__ mask,
                                                  u64* __restrict__ zbits) {
    int idx = blockIdx.x * 256 + threadIdx.x;     // pixel index, grid exact
    bool isz = mask[idx] < 0.5f;                  // zero (background) pixel
    u64 w = __ballot(isz);                        // lanes are 64 consecutive x
    if ((threadIdx.x & 63) == 0) zbits[idx >> 6] = w;
}

__device__ __forceinline__ int rowdist(const u64* __restrict__ zr, int x) {
    // distance from column x to nearest set bit in this 384-bit row
    const int w = x >> 6, xin = x & 63;
    const u64 cur = zr[w];
    int dr = NOZERO_DIST, dl = NOZERO_DIST;
    u64 t = cur >> xin;                           // bits at positions >= x
    if (t) {
        dr = __ffsll((long long)t) - 1;
    } else {
        for (int ww = w + 1; ww < WPR; ++ww) {
            u64 v = zr[ww];
            if (v) { dr = (ww << 6) + __ffsll((long long)v) - 1 - x; break; }
        }
    }
    u64 u = cur << (63 - xin);                    // bit x -> bit 63
    if (u) {
        dl = __clzll((long long)u);
    } else {
        for (int ww = w - 1; ww >= 0; --ww) {
            u64 v = zr[ww];
            if (v) { dl = x - ((ww << 6) + 63 - __clzll((long long)v)); break; }
        }
    }
    return min(dl, dr);                           // NOZERO_DIST if row has no zeros
}

__global__ __launch_bounds__(256) void edt_solve(const u64* __restrict__ zbits,
                                                 float* __restrict__ out) {
    int idx = blockIdx.x * 256 + threadIdx.x;
    int x = idx % WW;
    int y = (idx / WW) % HH;
    int b = idx / (WW * HH);
    const u64* zi = zbits + b * (HH * WPR);

    int r0 = rowdist(zi + y * WPR, x);
    int best = r0 * r0;                           // dy=0 term (== LARGE if row zero-free)
    for (int dy = 1; dy < HH; ++dy) {
        int dd = dy * dy;
        if (dd >= best) break;                    // exact cutoff
        if (y - dy >= 0) {
            int r = rowdist(zi + (y - dy) * WPR, x);
            best = min(best, dd + r * r);
        }
        if (y + dy < HH) {
            int r = rowdist(zi + (y + dy) * WPR, x);
            best = min(best, dd + r * r);
        }
    }
    out[idx] = sqrtf((float)best);
}

// ---------- fallback (ws too small): brute-force LDS version ----------

__global__ __launch_bounds__(WW) void edt_pass1(const float* __restrict__ mask,
                                                float* __restrict__ g) {
    const int row = blockIdx.x;
    const int x = threadIdx.x;
    __shared__ float f[WW];
    const float* m = mask + (size_t)row * WW;
    f[x] = (m[x] > 0.5f) ? LARGE_F : 0.0f;
    __syncthreads();
    float best = 1.0e30f;
    #pragma unroll 8
    for (int j = 0; j < WW; ++j) {
        float d = (float)(x - j);
        best = fminf(best, fmaf(d, d, f[j]));
    }
    g[(size_t)row * WW + x] = best;
}

__global__ __launch_bounds__(HH) void edt_pass2(float* __restrict__ g) {
    const int b = blockIdx.x / WW;
    const int x = blockIdx.x % WW;
    const int y = threadIdx.x;
    __shared__ float f[HH];
    f[y] = g[((size_t)b * HH + y) * WW + x];
    __syncthreads();
    float best = 1.0e30f;
    #pragma unroll 8
    for (int j = 0; j < HH; ++j) {
        float d = (float)(y - j);
        best = fminf(best, fmaf(d, d, f[j]));
    }
    g[((size_t)b * HH + y) * WW + x] = sqrtf(best);
}

extern "C" void kernel_launch(void* const* d_in, const int* in_sizes, int n_in,
                              void* d_out, int out_size, void* d_ws, size_t ws_size,
                              hipStream_t stream) {
    const float* mask = (const float*)d_in[0];
    float* out = (float*)d_out;

    if (ws_size >= (size_t)NWORDS * sizeof(u64)) {
        u64* zbits = (u64*)d_ws;
        const int nb = NPIX / 256;                 // exact: 2304 blocks
        pack_zbits<<<nb, 256, 0, stream>>>(mask, zbits);
        edt_solve<<<nb, 256, 0, stream>>>(zbits, out);
    } else {
        // Deterministic fallback: brute force, intermediate in d_out (in-place).
        edt_pass1<<<NB * HH, WW, 0, stream>>>(mask, out);
        edt_pass2<<<NB * WW, HH, 0, stream>>>(out);
    }
}